// Round 24
// baseline (82.295 us; speedup 1.0000x reference)
//
#include <hip/hip_runtime.h>
#include <math.h>

// V=4 views, N=8192 points, 6 directed chamfer terms (pair p rows=view pi, min over view pj)
#define VNUM   4
#define NPAIRS 6
#define BLK    256
#define QTILE  2048   // b-points per block (quarter of N)
#define CHUNK  1024   // b-points staged per LDS phase (32 KB)

using short8  = __attribute__((ext_vector_type(8)))  short;
using f32x16  = __attribute__((ext_vector_type(16))) float;

__device__ inline unsigned short f2bf(float x) {           // RNE to bf16
    unsigned u = __float_as_uint(x);
    return (unsigned short)((u + 0x7FFFu + ((u >> 16) & 1u)) >> 16);
}
__device__ inline float bf2f(unsigned short b) {
    return __uint_as_float(((unsigned)b) << 16);
}

// world-transform + hi/lo bf16 split (s = |p|^2) -- verified in R7/R21
__device__ inline void xform_split_v(const float* __restrict__ P,
                                     float px, float py, float pz,
                                     unsigned short& xh, unsigned short& xl,
                                     unsigned short& yh, unsigned short& yl,
                                     unsigned short& zh, unsigned short& zl,
                                     unsigned short& sh, unsigned short& sl) {
    float x = fmaf(P[0], px, fmaf(P[1], py, fmaf(P[2],  pz, P[3])));
    float y = fmaf(P[4], px, fmaf(P[5], py, fmaf(P[6],  pz, P[7])));
    float z = fmaf(P[8], px, fmaf(P[9], py, fmaf(P[10], pz, P[11])));
    float s = fmaf(x, x, fmaf(y, y, z * z));
    xh = f2bf(x); xl = f2bf(x - bf2f(xh));
    yh = f2bf(y); yl = f2bf(y - bf2f(yh));
    zh = f2bf(z); zl = f2bf(z - bf2f(zh));
    sh = f2bf(s); sl = f2bf(s - bf2f(sh));
}

// Fully fused single compute kernel. R23 chamfer body byte-identical through
// the epilogue stores. Tail: done-counter (memset-zeroed); the 4th x-block
// of each (pair, 256-row chunk) finalizes those rows via device-coherent
// atomicMin-reads, accumulates into ws scalar; 192nd winner writes d_out.
// __attribute__((amdgpu_waves_per_eu(3,4))) pins the allocator's occupancy
// target to 3-4 waves/EU so the tail cannot trigger the 8-wave/60-VGPR
// regalloc collapse seen in R7/R15/R18.
__global__ __launch_bounds__(BLK)
__attribute__((amdgpu_waves_per_eu(3, 4)))
void chamfer_kernel(const float* __restrict__ pts,
                    const float* __restrict__ poses,
                    float* __restrict__ minbuf,
                    unsigned int* __restrict__ done,
                    unsigned int* __restrict__ fin,
                    float* __restrict__ accum,
                    float* __restrict__ out, int N, float scale) {
    __shared__ short8 sbuf[CHUNK * 2];            // 32 KB: [hi x1024][lo x1024]
    const int p  = blockIdx.z;
    const int pi = (p < 3) ? 0 : ((p < 5) ? 1 : 2);
    const int pj = (p < 3) ? (p + 1) : ((p < 5) ? (p - 1) : 3);
    const int tid  = threadIdx.x;
    const int w    = tid >> 6;
    const int l    = tid & 63;
    const int col  = l & 31;
    const int half = l >> 5;

    const int abase = (blockIdx.y * 4 + w) * 64;  // 64 a-rows per wave
    const int b0    = blockIdx.x * QTILE;
    const float* Pi = poses + pi * 16;
    const float* Pj = poses + pj * 16;
    const short one = (short)0x3F80;

    // ---- A-fragments for this lane's two a-points (R7/R21-verified) ----
    short8 A0, A1;
#pragma unroll
    for (int q = 0; q < 2; ++q) {
        int r = pi * N + abase + col + q * 32;
        unsigned short xh, xl, yh, yl, zh, zl, sh, sl;
        xform_split_v(Pi, pts[r*3], pts[r*3+1], pts[r*3+2],
                      xh, xl, yh, yl, zh, zl, sh, sl);
        short8 e07, e8f;
        e07[0]=(short)xh; e07[1]=(short)yh; e07[2]=(short)zh; e07[3]=(short)xh;
        e07[4]=(short)yh; e07[5]=(short)zh; e07[6]=(short)xl; e07[7]=(short)yl;
        e8f[0]=(short)zl; e8f[1]=(short)sh; e8f[2]=(short)sl; e8f[3]=one;
        e8f[4]=one;       e8f[5]=(short)xl; e8f[6]=(short)yl; e8f[7]=(short)zl;
        short8 Av; if (half) Av = e8f; else Av = e07;
        if (q == 0) A0 = Av; else A1 = Av;
    }

    f32x16 m0, m1, zz;
#pragma unroll
    for (int i = 0; i < 16; ++i) { m0[i] = 3.402823466e38f; m1[i] = 3.402823466e38f; zz[i] = 0.0f; }

    for (int c = 0; c < QTILE / CHUNK; ++c) {
        __syncthreads();                          // previous phase fully consumed
        const float* bp = pts + ((size_t)(pj * N + b0 + c * CHUNK)) * 3;
#pragma unroll
        for (int k = 0; k < CHUNK / BLK; ++k) {   // 4 b-points per thread
            int i = k * BLK + tid;
            unsigned short xh, xl, yh, yl, zh, zl, sh, sl;
            xform_split_v(Pj, bp[i*3], bp[i*3+1], bp[i*3+2],
                          xh, xl, yh, yl, zh, zl, sh, sl);
            // -2 * bf16 piece is exact (power-of-two scale)
            short bxh=(short)f2bf(-2.0f*bf2f(xh)), byh=(short)f2bf(-2.0f*bf2f(yh)),
                  bzh=(short)f2bf(-2.0f*bf2f(zh));
            short bxl=(short)f2bf(-2.0f*bf2f(xl)), byl=(short)f2bf(-2.0f*bf2f(yl)),
                  bzl=(short)f2bf(-2.0f*bf2f(zl));
            short8 hi8, lo8;
            hi8[0]=bxh; hi8[1]=byh; hi8[2]=bzh; hi8[3]=bxl;
            hi8[4]=byl; hi8[5]=bzl; hi8[6]=bxh; hi8[7]=byh;
            lo8[0]=bzh; lo8[1]=one; lo8[2]=one; lo8[3]=(short)sh;
            lo8[4]=(short)sl; lo8[5]=bxl; lo8[6]=byl; lo8[7]=bzl;
            sbuf[i] = hi8; sbuf[CHUNK + i] = lo8;
        }
        __syncthreads();

        const short8* bsel = half ? (sbuf + CHUNK) : sbuf;
        for (int t = 0; t < CHUNK / 32; t += 2) { // 2 b-tiles per iteration
            short8 B0 = bsel[t * 32 + col];
            short8 B1 = bsel[(t + 1) * 32 + col];
            f32x16 d0 = __builtin_amdgcn_mfma_f32_32x32x16_bf16(A0, B0, zz, 0, 0, 0);
            f32x16 d1 = __builtin_amdgcn_mfma_f32_32x32x16_bf16(A0, B1, zz, 0, 0, 0);
#pragma unroll
            for (int i = 0; i < 16; ++i)          // fminf only -> v_min3 fusion
                m0[i] = fminf(m0[i], fminf(d0[i], d1[i]));
            d0 = __builtin_amdgcn_mfma_f32_32x32x16_bf16(A1, B0, zz, 0, 0, 0);
            d1 = __builtin_amdgcn_mfma_f32_32x32x16_bf16(A1, B1, zz, 0, 0, 0);
#pragma unroll
            for (int i = 0; i < 16; ++i)
                m1[i] = fminf(m1[i], fminf(d0[i], d1[i]));
        }
    }

    // ---- epilogue: butterfly min across the 32 lanes of each half ----
#pragma unroll
    for (int off = 1; off <= 16; off <<= 1) {
#pragma unroll
        for (int i = 0; i < 16; ++i) {
            m0[i] = fminf(m0[i], __shfl_xor(m0[i], off, 64));
            m1[i] = fminf(m1[i], __shfl_xor(m1[i], off, 64));
        }
    }
    if (col == 0) {
        // plain stores: per-x-block slot, no init, no atomics
        float* fm = minbuf + ((size_t)(p * 4 + blockIdx.x)) * N + abase;
#pragma unroll
        for (int r = 0; r < 16; ++r) {
            int row = (r & 3) + 8 * (r >> 2) + 4 * half;   // verified C/D mapping
            fm[row]      = fmaxf(m0[r], 0.0f);
            fm[32 + row] = fmaxf(m1[r], 0.0f);
        }
    }

    // ---- fused finalize (wave 0 only, LDS-free) ----
    __threadfence();                              // release stores before count
    __syncthreads();
    if (w == 0) {
        unsigned old = 0;
        if (l == 0) old = atomicAdd(&done[p * 32 + blockIdx.y], 1u);
        old = (unsigned)__shfl((int)old, 0, 64);  // wave-uniform
        if (old == 3u) {                          // 4th block of this group
            unsigned* mbu = (unsigned*)minbuf;
            const int rbase = blockIdx.y * 256;
            float s = 0.0f;
#pragma unroll
            for (int k = 0; k < 4; ++k) {
                int row = rbase + l + k * 64;
                float d2 = 3.402823466e38f;
#pragma unroll
                for (int x = 0; x < 4; ++x) {     // device-coherent no-op-min read
                    unsigned v = atomicMin(&mbu[((size_t)(p * 4 + x)) * N + row],
                                           0x7F7F7F7Fu);
                    d2 = fminf(d2, __uint_as_float(v));
                }
                s += sqrtf(d2);
            }
#pragma unroll
            for (int off = 32; off >= 1; off >>= 1)
                s += __shfl_down(s, off, 64);
            if (l == 0) {
                atomicAdd(accum, s * scale);
                __threadfence();                  // accum visible before count
                unsigned f = atomicAdd(fin, 1u);
                if (f == NPAIRS * 32 - 1u) {      // 192nd (last) winner
                    float tot = atomicAdd(accum, 0.0f);   // coherent read
                    *out = tot;
                }
            }
        }
    }
}

extern "C" void kernel_launch(void* const* d_in, const int* in_sizes, int n_in,
                              void* d_out, int out_size, void* d_ws, size_t ws_size,
                              hipStream_t stream) {
    const float* points = (const float*)d_in[0];   // V x N x 3 fp32
    const float* poses  = (const float*)d_in[1];   // V x 4 x 4 fp32
    float* out = (float*)d_out;                    // scalar fp32

    const int N = in_sizes[0] / (VNUM * 3);        // 8192

    // ws: minbuf float[6][4][N] (786 KB, plain stores - no init) |
    //     done uint[192] | fin uint | accum float   (zeroed by one tiny memset)
    float* minbuf = (float*)d_ws;
    unsigned int* done = (unsigned int*)((char*)d_ws +
                         (size_t)NPAIRS * 4 * N * sizeof(float));
    unsigned int* fin  = done + NPAIRS * 32;
    float* accum       = (float*)(fin + 1);

    hipMemsetAsync(done, 0, (NPAIRS * 32 + 2) * sizeof(unsigned int), stream);

    dim3 grid(N / QTILE, N / 256, NPAIRS);         // 4 x 32 x 6 = 768 blocks
    chamfer_kernel<<<grid, BLK, 0, stream>>>(points, poses, minbuf, done, fin,
                                             accum, out, N,
                                             1.0f / (6.0f * (float)N));
}

// Round 25
// 29.147 us; speedup vs baseline: 2.8234x; 2.8234x over previous
//
#include <hip/hip_runtime.h>
#include <math.h>

// V=4 views, N=8192 points, 6 directed chamfer terms (pair p rows=view pi, min over view pj)
#define VNUM   4
#define NPAIRS 6
#define BLK    256
#define QTILE  2048   // b-points per block (quarter of N)
#define CHUNK  1024   // b-points staged per LDS phase (32 KB)

using short8  = __attribute__((ext_vector_type(8)))  short;
using f32x16  = __attribute__((ext_vector_type(16))) float;

__device__ inline unsigned short f2bf(float x) {           // RNE to bf16
    unsigned u = __float_as_uint(x);
    return (unsigned short)((u + 0x7FFFu + ((u >> 16) & 1u)) >> 16);
}
__device__ inline float bf2f(unsigned short b) {
    return __uint_as_float(((unsigned)b) << 16);
}

// world-transform + hi/lo bf16 split (s = |p|^2) -- verified in R7/R21
__device__ inline void xform_split_v(const float* __restrict__ P,
                                     float px, float py, float pz,
                                     unsigned short& xh, unsigned short& xl,
                                     unsigned short& yh, unsigned short& yl,
                                     unsigned short& zh, unsigned short& zl,
                                     unsigned short& sh, unsigned short& sl) {
    float x = fmaf(P[0], px, fmaf(P[1], py, fmaf(P[2],  pz, P[3])));
    float y = fmaf(P[4], px, fmaf(P[5], py, fmaf(P[6],  pz, P[7])));
    float z = fmaf(P[8], px, fmaf(P[9], py, fmaf(P[10], pz, P[11])));
    float s = fmaf(x, x, fmaf(y, y, z * z));
    xh = f2bf(x); xl = f2bf(x - bf2f(xh));
    yh = f2bf(y); yl = f2bf(y - bf2f(yh));
    zh = f2bf(z); zl = f2bf(z - bf2f(zh));
    sh = f2bf(s); sl = f2bf(s - bf2f(sh));
}

// Kernel 1 (of 2): fused fragment-build + chamfer (R23 champion, final).
// A-frags built in registers (dot(A,B) = |a|^2+|b|^2-2(a_hi+a_lo).(b_hi+b_lo));
// B-frags transformed per 1024-pt chunk into LDS ([hi x1024][lo x1024]).
// Epilogue: plain per-x-block stores (no init, no atomics). NO coherence
// tail here -- 4/4 fusion attempts (R7/R15/R18/R24) collapsed regalloc to
// 48-60 VGPR regardless of noinline / launch_bounds / waves_per_eu shields.
__global__ __launch_bounds__(BLK, 3)
void chamfer_kernel(const float* __restrict__ pts,
                    const float* __restrict__ poses,
                    float* __restrict__ minbuf,
                    float* __restrict__ out, int N) {
    __shared__ short8 sbuf[CHUNK * 2];            // 32 KB: [hi x1024][lo x1024]
    const int p  = blockIdx.z;
    const int pi = (p < 3) ? 0 : ((p < 5) ? 1 : 2);
    const int pj = (p < 3) ? (p + 1) : ((p < 5) ? (p - 1) : 3);
    const int tid  = threadIdx.x;
    const int w    = tid >> 6;
    const int l    = tid & 63;
    const int col  = l & 31;
    const int half = l >> 5;

    const int abase = (blockIdx.y * 4 + w) * 64;  // 64 a-rows per wave
    const int b0    = blockIdx.x * QTILE;
    const float* Pi = poses + pi * 16;
    const float* Pj = poses + pj * 16;
    const short one = (short)0x3F80;

    if (blockIdx.x == 0 && blockIdx.y == 0 && p == 0 && tid == 0)
        *out = 0.0f;                              // finalize runs strictly after

    // ---- A-fragments for this lane's two a-points ----
    short8 A0, A1;
#pragma unroll
    for (int q = 0; q < 2; ++q) {
        int r = pi * N + abase + col + q * 32;
        unsigned short xh, xl, yh, yl, zh, zl, sh, sl;
        xform_split_v(Pi, pts[r*3], pts[r*3+1], pts[r*3+2],
                      xh, xl, yh, yl, zh, zl, sh, sl);
        short8 e07, e8f;
        e07[0]=(short)xh; e07[1]=(short)yh; e07[2]=(short)zh; e07[3]=(short)xh;
        e07[4]=(short)yh; e07[5]=(short)zh; e07[6]=(short)xl; e07[7]=(short)yl;
        e8f[0]=(short)zl; e8f[1]=(short)sh; e8f[2]=(short)sl; e8f[3]=one;
        e8f[4]=one;       e8f[5]=(short)xl; e8f[6]=(short)yl; e8f[7]=(short)zl;
        short8 Av; if (half) Av = e8f; else Av = e07;
        if (q == 0) A0 = Av; else A1 = Av;
    }

    f32x16 m0, m1, zz;
#pragma unroll
    for (int i = 0; i < 16; ++i) { m0[i] = 3.402823466e38f; m1[i] = 3.402823466e38f; zz[i] = 0.0f; }

    for (int c = 0; c < QTILE / CHUNK; ++c) {
        __syncthreads();                          // previous phase fully consumed
        const float* bp = pts + ((size_t)(pj * N + b0 + c * CHUNK)) * 3;
#pragma unroll
        for (int k = 0; k < CHUNK / BLK; ++k) {   // 4 b-points per thread
            int i = k * BLK + tid;
            unsigned short xh, xl, yh, yl, zh, zl, sh, sl;
            xform_split_v(Pj, bp[i*3], bp[i*3+1], bp[i*3+2],
                          xh, xl, yh, yl, zh, zl, sh, sl);
            // -2 * bf16 piece is exact (power-of-two scale)
            short bxh=(short)f2bf(-2.0f*bf2f(xh)), byh=(short)f2bf(-2.0f*bf2f(yh)),
                  bzh=(short)f2bf(-2.0f*bf2f(zh));
            short bxl=(short)f2bf(-2.0f*bf2f(xl)), byl=(short)f2bf(-2.0f*bf2f(yl)),
                  bzl=(short)f2bf(-2.0f*bf2f(zl));
            short8 hi8, lo8;
            hi8[0]=bxh; hi8[1]=byh; hi8[2]=bzh; hi8[3]=bxl;
            hi8[4]=byl; hi8[5]=bzl; hi8[6]=bxh; hi8[7]=byh;
            lo8[0]=bzh; lo8[1]=one; lo8[2]=one; lo8[3]=(short)sh;
            lo8[4]=(short)sl; lo8[5]=bxl; lo8[6]=byl; lo8[7]=bzl;
            sbuf[i] = hi8; sbuf[CHUNK + i] = lo8;
        }
        __syncthreads();

        const short8* bsel = half ? (sbuf + CHUNK) : sbuf;
        for (int t = 0; t < CHUNK / 32; t += 2) { // 2 b-tiles per iteration
            short8 B0 = bsel[t * 32 + col];
            short8 B1 = bsel[(t + 1) * 32 + col];
            f32x16 d0 = __builtin_amdgcn_mfma_f32_32x32x16_bf16(A0, B0, zz, 0, 0, 0);
            f32x16 d1 = __builtin_amdgcn_mfma_f32_32x32x16_bf16(A0, B1, zz, 0, 0, 0);
#pragma unroll
            for (int i = 0; i < 16; ++i)          // fminf only -> v_min3 fusion
                m0[i] = fminf(m0[i], fminf(d0[i], d1[i]));
            d0 = __builtin_amdgcn_mfma_f32_32x32x16_bf16(A1, B0, zz, 0, 0, 0);
            d1 = __builtin_amdgcn_mfma_f32_32x32x16_bf16(A1, B1, zz, 0, 0, 0);
#pragma unroll
            for (int i = 0; i < 16; ++i)
                m1[i] = fminf(m1[i], fminf(d0[i], d1[i]));
        }
    }

    // ---- epilogue: butterfly min across the 32 lanes of each half ----
#pragma unroll
    for (int off = 1; off <= 16; off <<= 1) {
#pragma unroll
        for (int i = 0; i < 16; ++i) {
            m0[i] = fminf(m0[i], __shfl_xor(m0[i], off, 64));
            m1[i] = fminf(m1[i], __shfl_xor(m1[i], off, 64));
        }
    }
    if (col == 0) {
        // plain stores: per-x-block slot, no init, no atomics
        float* fm = minbuf + ((size_t)(p * 4 + blockIdx.x)) * N + abase;
#pragma unroll
        for (int r = 0; r < 16; ++r) {
            int row = (r & 3) + 8 * (r >> 2) + 4 * half;   // verified C/D mapping
            fm[row]      = fmaxf(m0[r], 0.0f);
            fm[32 + row] = fmaxf(m1[r], 0.0f);
        }
    }
}

// Kernel 2 (of 2): row d^2 = min over the 4 x-block slots; d = sqrt;
// block-reduce; scaled atomicAdd into scalar out (zeroed by chamfer).
__global__ void finalize_kernel(const float* __restrict__ minbuf,
                                float* __restrict__ out, float scale, int N) {
    __shared__ float red[BLK / 64];
    int idx = blockIdx.x * blockDim.x + threadIdx.x;   // 0 .. 6*N-1
    int p   = idx / N;
    int row = idx - p * N;
    const float* fm = minbuf + ((size_t)p * 4) * N + row;
    float d2 = fminf(fminf(fm[0], fm[(size_t)N]),
                     fminf(fm[(size_t)2 * N], fm[(size_t)3 * N]));
    float d = sqrtf(d2);
#pragma unroll
    for (int off = 32; off >= 1; off >>= 1)
        d += __shfl_down(d, off, 64);
    int lane = threadIdx.x & 63;
    int wid  = threadIdx.x >> 6;
    if (lane == 0) red[wid] = d;
    __syncthreads();
    if (threadIdx.x == 0) {
        float s = 0.0f;
#pragma unroll
        for (int wv = 0; wv < BLK / 64; ++wv) s += red[wv];
        atomicAdd(out, s * scale);
    }
}

extern "C" void kernel_launch(void* const* d_in, const int* in_sizes, int n_in,
                              void* d_out, int out_size, void* d_ws, size_t ws_size,
                              hipStream_t stream) {
    const float* points = (const float*)d_in[0];   // V x N x 3 fp32
    const float* poses  = (const float*)d_in[1];   // V x 4 x 4 fp32
    float* out = (float*)d_out;                    // scalar fp32

    const int N = in_sizes[0] / (VNUM * 3);        // 8192

    // ws: minbuf float[6][4][N] = 786 KB (plain stores, no init needed)
    float* minbuf = (float*)d_ws;

    dim3 grid(N / QTILE, N / 256, NPAIRS);         // 4 x 32 x 6 = 768 blocks
    chamfer_kernel<<<grid, BLK, 0, stream>>>(points, poses, minbuf, out, N);

    finalize_kernel<<<(NPAIRS * N) / BLK, BLK, 0, stream>>>(
        minbuf, out, 1.0f / (6.0f * (float)N), N);
}